// Round 6
// baseline (307.164 us; speedup 1.0000x reference)
//
#include <hip/hip_runtime.h>
#include <math.h>
#include <stdint.h>

#define Bb 8
#define Tt 4
#define Ll 512
#define Dd 512
#define Hh 8
#define HDd 64
#define Mm (Bb*Tt*Ll)   // 16384 rows

typedef _Float16 f16;
typedef _Float16 f16x8 __attribute__((ext_vector_type(8)));
typedef _Float16 f16x4 __attribute__((ext_vector_type(4)));
typedef float f32x16 __attribute__((ext_vector_type(16)));

#define LO_SCALE 2048.0f
#define LO_INV   4.8828125e-4f   // 1/2048 exact

__device__ __forceinline__ void gload16(const void* g, void* l) {
  __builtin_amdgcn_global_load_lds(
      (const __attribute__((address_space(1))) unsigned int*)(uintptr_t)g,
      (__attribute__((address_space(3))) unsigned int*)(uintptr_t)l,
      16, 0, 0);
}

// ---------------- split: f32 -> (hi f16, lo f16 scaled by 2048) ----------------
struct SplitArgs {
  const float* src[5];
  f16* hi[5];
  f16* lo[5];
};

__global__ void split_k(SplitArgs s) {
  int i = blockIdx.x * 256 + threadIdx.x;
  int seg, base;
  if (i < 1048576) { seg = 0; base = i; }
  else { int r = i - 1048576; seg = 1 + (r >> 15); base = r & 32767; }
  const float* sp = s.src[seg] + (size_t)base * 8;
  float4 v0 = *(const float4*)sp;
  float4 v1 = *(const float4*)(sp + 4);
  float a[8] = {v0.x, v0.y, v0.z, v0.w, v1.x, v1.y, v1.z, v1.w};
  f16x8 hv, lv;
  #pragma unroll
  for (int e = 0; e < 8; ++e) {
    f16 hh = (f16)a[e];
    hv[e] = hh;
    lv[e] = (f16)((a[e] - (float)hh) * LO_SCALE);
  }
  *(f16x8*)(s.hi[seg] + (size_t)base * 8) = hv;
  *(f16x8*)(s.lo[seg] + (size_t)base * 8) = lv;
}

// ---------------- f16x2 MFMA GEMM, 32x32x16 frags, dbuf, fused BN+LIF ----------------
// Row mapping: by in [0,128): b = by>>4, lc32 = by&15.
// tile_row r in [0,128): t = r>>5, rl = r&31; global row = (b*4+t)*512 + lc32*32 + rl.
struct GArgs {
  const f16 *Ah, *Al;
  const f16 *Wh0, *Wl0, *Wh1, *Wl1, *Wh2, *Wl2;
  const float *g0,*b0,*rm0,*rv0;
  const float *g1,*b1,*rm1,*rv1;
  const float *g2,*b2,*rm2,*rv2;
  const float* bias;   // MODE==1 only
  f16*   oq;   // MODE0 seg0: q spikes (f16 exact {0,1})
  float* ok;   // MODE0 seg1: relu(BN(k)) f32
  f16*   ov;   // MODE0 seg2: ternary v (f16 exact {-1,0,1})
  float* oo;   // MODE1: final spikes f32 (d_out)
};

#define SMEM_BYTES 65536   // 2 dbuf slots x 32KB (Ah/Al/Bh/Bl [128][32] f16 each)

template<int MODE>
__global__ __launch_bounds__(256, 2)
void gemm_f16(GArgs ar) {
  extern __shared__ __align__(16) char smem[];
  float (*TS)[133] = (float(*)[133])smem;  // [64 cols][128 rows + pad] (overlays slot0)

  const int tid = threadIdx.x;
  const int lane = tid & 63, wid = tid >> 6;

  // XCD-chunked swizzle: grid is 1D; each XCD gets contiguous row-panels.
  const int bid = blockIdx.x;
  int bx, by;
  if (MODE == 0) { const int sw = (bid & 7) * 192 + (bid >> 3); bx = sw % 12; by = sw / 12; }
  else           { const int sw = (bid & 7) * 64  + (bid >> 3); bx = sw & 3;  by = sw >> 2; }

  const int seg = (MODE == 0) ? (bx >> 2) : 0;
  const int lc0 = (MODE == 0) ? ((bx & 3) << 7) : (bx << 7);
  const int b = by >> 4, lc32 = by & 15;

  const f16* Wh = (seg == 0 ? ar.Wh0 : (seg == 1 ? ar.Wh1 : ar.Wh2));
  const f16* Wl = (seg == 0 ? ar.Wl0 : (seg == 1 ? ar.Wl1 : ar.Wl2));
  const float* gp  = (seg == 0 ? ar.g0  : (seg == 1 ? ar.g1  : ar.g2));
  const float* bp  = (seg == 0 ? ar.b0  : (seg == 1 ? ar.b1  : ar.b2));
  const float* rmp = (seg == 0 ? ar.rm0 : (seg == 1 ? ar.rm1 : ar.rm2));
  const float* rvp = (seg == 0 ? ar.rv0 : (seg == 1 ? ar.rv1 : ar.rv2));

  const int sr = lane >> 2, skc = lane & 3;
  const int skcs = skc ^ (sr & 3);              // source-side chunk swizzle (involution)
  const int frow = lane & 31, khalf = lane >> 5;
  const int wmr = wid >> 1, wnc = wid & 1;      // wave 2x2 -> 64x64 per wave

  f32x16 acc_h[2][2], acc_l[2][2];
  #pragma unroll
  for (int i = 0; i < 2; ++i)
    #pragma unroll
    for (int j = 0; j < 2; ++j) {
      acc_h[i][j] = (f32x16)0.0f;
      acc_l[i][j] = (f32x16)0.0f;
    }

  // stage K-tile k0 into dbuf slot
  #define STAGE(k0_, slot_)                                                        \
    {                                                                              \
      char* sb = smem + (slot_) * 32768;                                           \
      _Pragma("unroll")                                                            \
      for (int i = 0; i < 2; ++i) {                                                \
        const int r = i * 64 + wid * 16 + sr;                                      \
        const int growA = (((b << 2) + (r >> 5)) << 9) + (lc32 << 5) + (r & 31);   \
        const size_t goA = (size_t)growA * Dd + (k0_) + skcs * 8;                  \
        const size_t goB = (size_t)(lc0 + r) * Dd + (k0_) + skcs * 8;              \
        const int lb = i * 2048 + wid * 512;                                       \
        gload16(ar.Ah + goA, (f16*)sb + lb);                                       \
        gload16(ar.Al + goA, (f16*)(sb + 8192) + lb);                              \
        gload16(Wh + goB, (f16*)(sb + 16384) + lb);                                \
        gload16(Wl + goB, (f16*)(sb + 24576) + lb);                                \
      }                                                                            \
    }

  STAGE(0, 0);
  __syncthreads();

  for (int t = 0; t < 16; ++t) {
    const int cur = t & 1;
    const f16* Ahs = (const f16*)(smem + cur * 32768);
    const f16* Als = Ahs + 4096;
    const f16* Bhs = Ahs + 8192;
    const f16* Bls = Ahs + 12288;

    if (t < 15) STAGE((t + 1) * 32, cur ^ 1);   // prefetch next tile into other slot

    f16x8 ah[2][2], al[2][2], bh[2][2], bl[2][2];   // [frag][kstep]
    #pragma unroll
    for (int mi = 0; mi < 2; ++mi) {
      const int r = wmr * 64 + mi * 32 + frow;
      #pragma unroll
      for (int ks = 0; ks < 2; ++ks) {
        const int cin = (khalf + 2 * ks) ^ (lane & 3);   // read-side swizzle
        const int ad = r * 32 + cin * 8;
        ah[mi][ks] = *(const f16x8*)&Ahs[ad];
        al[mi][ks] = *(const f16x8*)&Als[ad];
      }
    }
    #pragma unroll
    for (int nj = 0; nj < 2; ++nj) {
      const int r = wnc * 64 + nj * 32 + frow;
      #pragma unroll
      for (int ks = 0; ks < 2; ++ks) {
        const int cin = (khalf + 2 * ks) ^ (lane & 3);
        const int ad = r * 32 + cin * 8;
        bh[nj][ks] = *(const f16x8*)&Bhs[ad];
        bl[nj][ks] = *(const f16x8*)&Bls[ad];
      }
    }
    #pragma unroll
    for (int ks = 0; ks < 2; ++ks)
      #pragma unroll
      for (int mi = 0; mi < 2; ++mi)
        #pragma unroll
        for (int nj = 0; nj < 2; ++nj) {
          acc_h[mi][nj] = __builtin_amdgcn_mfma_f32_32x32x16_f16(ah[mi][ks], bh[nj][ks], acc_h[mi][nj], 0, 0, 0);
          acc_l[mi][nj] = __builtin_amdgcn_mfma_f32_32x32x16_f16(ah[mi][ks], bl[nj][ks], acc_l[mi][nj], 0, 0, 0);
          acc_l[mi][nj] = __builtin_amdgcn_mfma_f32_32x32x16_f16(al[mi][ks], bh[nj][ks], acc_l[mi][nj], 0, 0, 0);
        }
    __syncthreads();   // vmcnt(0): t+1 loads landed (hidden under MFMAs); barrier
  }
  #undef STAGE

  // per-column BN constants (2 cols per thread: one per nj-frag)
  float scl[2], shc[2];
  #pragma unroll
  for (int nj = 0; nj < 2; ++nj) {
    const int c = lc0 + wnc * 64 + nj * 32 + frow;
    double S = (double)gp[c] / sqrt((double)rvp[c] + 1e-5);
    double Sh = (double)bp[c] - (double)rmp[c] * S;
    if (MODE == 1) Sh += (double)ar.bias[c] * S;
    scl[nj] = (float)S; shc[nj] = (float)Sh;
  }

  if (MODE == 0 && seg != 0) {
    // direct-write path (k: relu f32, v: ternary f16)
    #pragma unroll
    for (int mi = 0; mi < 2; ++mi)
      #pragma unroll
      for (int nj = 0; nj < 2; ++nj)
        #pragma unroll
        for (int r = 0; r < 16; ++r) {
          const int row32 = (r & 3) + 8 * (r >> 2) + 4 * khalf;
          const int tr = wmr * 64 + mi * 32 + row32;
          const int grow = (((b << 2) + (tr >> 5)) << 9) + (lc32 << 5) + (tr & 31);
          const int col = lc0 + wnc * 64 + nj * 32 + frow;
          float val = acc_h[mi][nj][r] + acc_l[mi][nj][r] * LO_INV;
          float y = val * scl[nj] + shc[nj];
          if (seg == 1) ar.ok[(size_t)grow * Dd + col] = fmaxf(y, 0.f);
          else ar.ov[(size_t)grow * Dd + col] =
                   (f16)((y >= 1.f ? 1.f : 0.f) - (-y >= 1.f ? 1.f : 0.f));
        }
    return;
  }

  // fused BN + LIF epilogue, one 64-col half at a time via TS transpose
  #pragma unroll
  for (int half = 0; half < 2; ++half) {
    if (wnc == half) {
      #pragma unroll
      for (int mi = 0; mi < 2; ++mi)
        #pragma unroll
        for (int nj = 0; nj < 2; ++nj)
          #pragma unroll
          for (int q = 0; q < 4; ++q) {
            float4 yv;
            float* yp = &yv.x;
            #pragma unroll
            for (int rr = 0; rr < 4; ++rr) {
              const int r = q * 4 + rr;
              float val = acc_h[mi][nj][r] + acc_l[mi][nj][r] * LO_INV;
              yp[rr] = val * scl[nj] + shc[nj];
            }
            *(float4*)&TS[nj * 32 + frow][wmr * 64 + mi * 32 + 8 * q + 4 * khalf] = yv;
          }
    }
    __syncthreads();
    const int cc4 = (tid & 15) << 2;
    #pragma unroll
    for (int rr = 0; rr < 2; ++rr) {
      const int rl = (tid >> 4) + (rr << 4);
      float mm[4] = {0.f, 0.f, 0.f, 0.f};
      #pragma unroll
      for (int t = 0; t < 4; ++t) {
        const int trow = t * 32 + rl;
        float sp[4];
        #pragma unroll
        for (int c = 0; c < 4; ++c) {
          float y = TS[cc4 + c][trow];
          float rst = (mm[c] >= 1.f) ? 1.f : 0.f;
          mm[c] = 0.5f * mm[c] + y - rst;
          sp[c] = (mm[c] >= 1.f) ? 1.f : 0.f;
        }
        const size_t go = ((size_t)((((b << 2) + t) << 9) + (lc32 << 5) + rl)) * Dd
                          + lc0 + (half << 6) + cc4;
        if (MODE == 0) {
          f16x4 s4;
          s4[0] = (f16)sp[0]; s4[1] = (f16)sp[1]; s4[2] = (f16)sp[2]; s4[3] = (f16)sp[3];
          *(f16x4*)(ar.oq + go) = s4;
        } else {
          *(float4*)(ar.oo + go) = make_float4(sp[0], sp[1], sp[2], sp[3]);
        }
      }
    }
    __syncthreads();
  }
}

// ---------------- attention phase 1: partial G = 0.125 * k^T v (k f32, v f16) ----------------
__global__ __launch_bounds__(256)
void attn_g(const float* __restrict__ ks, const f16* __restrict__ vs,
            float* __restrict__ pG) {
  const int bt = blockIdx.x, h = blockIdx.y, c = blockIdx.z;
  const float* kp = ks + (size_t)bt * Ll * Dd + h * HDd;
  const f16* vp = vs + (size_t)bt * Ll * Dd + h * HDd;

  __shared__ float KS[64][68];
  __shared__ float VS[64][68];
  const int tid = threadIdx.x;
  const int te = tid & 15, td = tid >> 4;

  float gacc[4][4];
  #pragma unroll
  for (int i = 0; i < 4; ++i)
    #pragma unroll
    for (int j = 0; j < 4; ++j) gacc[i][j] = 0.f;

  for (int mt = 0; mt < 2; ++mt) {
    const int m0 = c * 128 + mt * 64;
    #pragma unroll
    for (int it = 0; it < 4; ++it) {
      int fidx = it * 256 + tid;
      int row = fidx >> 4, fq = fidx & 15;
      *(float4*)&KS[row][fq << 2] = *(const float4*)(kp + (size_t)(m0 + row) * Dd + (fq << 2));
    }
    #pragma unroll
    for (int it = 0; it < 2; ++it) {
      int fidx = it * 256 + tid;
      int row = fidx >> 3, c8 = fidx & 7;
      f16x8 hv = *(const f16x8*)(vp + (size_t)(m0 + row) * Dd + (c8 << 3));
      *(float4*)&VS[row][c8 << 3] = make_float4(hv[0], hv[1], hv[2], hv[3]);
      *(float4*)&VS[row][(c8 << 3) + 4] = make_float4(hv[4], hv[5], hv[6], hv[7]);
    }
    __syncthreads();
    #pragma unroll 4
    for (int mm = 0; mm < 64; ++mm) {
      float4 k4 = *(const float4*)&KS[mm][te << 2];
      float4 v4 = *(const float4*)&VS[mm][td << 2];
      const float kk[4] = {k4.x, k4.y, k4.z, k4.w};
      const float vv[4] = {v4.x, v4.y, v4.z, v4.w};
      #pragma unroll
      for (int i = 0; i < 4; ++i)
        #pragma unroll
        for (int j = 0; j < 4; ++j)
          gacc[i][j] = fmaf(kk[i], vv[j], gacc[i][j]);
    }
    __syncthreads();
  }
  float* out = pG + (((size_t)(bt * 8 + h) * 4 + c) << 12);
  #pragma unroll
  for (int i = 0; i < 4; ++i)
    *(float4*)&out[((te << 2) + i) * 64 + (td << 2)] =
        make_float4(gacc[i][0] * 0.125f, gacc[i][1] * 0.125f,
                    gacc[i][2] * 0.125f, gacc[i][3] * 0.125f);
}

// ---------------- attention phase 2: out = q @ G (q f16 spikes), hi/lo f16 output ----------------
__global__ __launch_bounds__(256)
void attn_o(const f16* __restrict__ qs, const float* __restrict__ pG,
            f16* __restrict__ ahi, f16* __restrict__ alo) {
  const int bt = blockIdx.x, h = blockIdx.y, lc = blockIdx.z;
  __shared__ float G[64][68];
  __shared__ float QS[64][68];
  const int tid = threadIdx.x;

  const float* pg = pG + (((size_t)(bt * 8 + h) * 4) << 12);
  #pragma unroll
  for (int rep = 0; rep < 4; ++rep) {
    int t4 = rep * 256 + tid;
    int e = t4 >> 4, dq = t4 & 15;
    int off = e * 64 + (dq << 2);
    float4 s0 = *(const float4*)(pg + off);
    float4 s1 = *(const float4*)(pg + 4096 + off);
    float4 s2 = *(const float4*)(pg + 8192 + off);
    float4 s3 = *(const float4*)(pg + 12288 + off);
    *(float4*)&G[e][dq << 2] = make_float4(s0.x + s1.x + s2.x + s3.x,
                                           s0.y + s1.y + s2.y + s3.y,
                                           s0.z + s1.z + s2.z + s3.z,
                                           s0.w + s1.w + s2.w + s3.w);
  }
  __syncthreads();

  const f16* qp = qs + (size_t)bt * Ll * Dd + h * HDd;
  const int lr = tid >> 2, dg = tid & 3;

  for (int l0 = 0; l0 < 128; l0 += 64) {
    #pragma unroll
    for (int it = 0; it < 2; ++it) {
      int fidx = it * 256 + tid;
      int row = fidx >> 3, c8 = fidx & 7;
      f16x8 hv = *(const f16x8*)(qp + (size_t)(lc * 128 + l0 + row) * Dd + (c8 << 3));
      *(float4*)&QS[row][c8 << 3] = make_float4(hv[0], hv[1], hv[2], hv[3]);
      *(float4*)&QS[row][(c8 << 3) + 4] = make_float4(hv[4], hv[5], hv[6], hv[7]);
    }
    __syncthreads();
    float oacc[16];
    #pragma unroll
    for (int j = 0; j < 16; ++j) oacc[j] = 0.f;
    for (int ee = 0; ee < 64; ++ee) {
      float qv = QS[lr][ee];
      #pragma unroll
      for (int jq = 0; jq < 4; ++jq) {
        float4 g4 = *(const float4*)&G[ee][(dg << 4) + (jq << 2)];
        oacc[jq * 4 + 0] = fmaf(qv, g4.x, oacc[jq * 4 + 0]);
        oacc[jq * 4 + 1] = fmaf(qv, g4.y, oacc[jq * 4 + 1]);
        oacc[jq * 4 + 2] = fmaf(qv, g4.z, oacc[jq * 4 + 2]);
        oacc[jq * 4 + 3] = fmaf(qv, g4.w, oacc[jq * 4 + 3]);
      }
    }
    f16x8 h0, l0v, h1, l1v;
    #pragma unroll
    for (int t = 0; t < 8; ++t) {
      float v = oacc[t];
      f16 hh = (f16)v;
      h0[t] = hh; l0v[t] = (f16)((v - (float)hh) * LO_SCALE);
      float v2 = oacc[8 + t];
      f16 hh2 = (f16)v2;
      h1[t] = hh2; l1v[t] = (f16)((v2 - (float)hh2) * LO_SCALE);
    }
    size_t ob = ((size_t)bt * Ll + lc * 128 + l0 + lr) * Dd + h * HDd + (dg << 4);
    *(f16x8*)(ahi + ob) = h0;
    *(f16x8*)(ahi + ob + 8) = h1;
    *(f16x8*)(alo + ob) = l0v;
    *(f16x8*)(alo + ob + 8) = l1v;
    __syncthreads();
  }
}

// ---------------- launch ----------------
extern "C" void kernel_launch(void* const* d_in, const int* in_sizes, int n_in,
                              void* d_out, int out_size, void* d_ws, size_t ws_size,
                              hipStream_t stream) {
  const float* x    = (const float*)d_in[0];
  const float* q_w  = (const float*)d_in[1];
  const float* q_g  = (const float*)d_in[2];
  const float* q_b  = (const float*)d_in[3];
  const float* q_rm = (const float*)d_in[4];
  const float* q_rv = (const float*)d_in[5];
  const float* k_w  = (const float*)d_in[6];
  const float* k_g  = (const float*)d_in[7];
  const float* k_b  = (const float*)d_in[8];
  const float* k_rm = (const float*)d_in[9];
  const float* k_rv = (const float*)d_in[10];
  const float* v_w  = (const float*)d_in[11];
  const float* v_g  = (const float*)d_in[12];
  const float* v_b  = (const float*)d_in[13];
  const float* v_rm = (const float*)d_in[14];
  const float* v_rv = (const float*)d_in[15];
  const float* o_w  = (const float*)d_in[16];
  const float* o_bias = (const float*)d_in[17];
  const float* o_g  = (const float*)d_in[18];
  const float* o_b  = (const float*)d_in[19];
  const float* o_rm = (const float*)d_in[20];
  const float* o_rv = (const float*)d_in[21];

  char* wsb = (char*)d_ws;
  const size_t R16 = 16777216;            // 16 MB = one NBUF of f16
  f16*   xhi  = (f16*)wsb;                // dead after QKV -> reused as ahi
  f16*   xlo  = (f16*)(wsb + R16);        // dead after QKV -> reused as alo
  f16*   qspk = (f16*)(wsb + 2 * R16);    // q spikes f16
  float* kbuf = (float*)(wsb + 3 * R16);  // relu(BN(k)) f32 (2 regions)
  f16*   vbuf = (f16*)(wsb + 5 * R16);    // ternary v f16
  float* pG   = (float*)(wsb + 6 * R16);  // partial G f32
  f16*   wsp  = (f16*)(wsb + 7 * R16);    // 8 x 262144 f16 = 4 MB weight splits
  f16* qwh = wsp;            f16* qwl = wsp + 262144;
  f16* kwh = wsp + 2*262144; f16* kwl = wsp + 3*262144;
  f16* vwh = wsp + 4*262144; f16* vwl = wsp + 5*262144;
  f16* owh = wsp + 6*262144; f16* owl = wsp + 7*262144;
  f16* ahi = xhi;
  f16* alo = xlo;

  SplitArgs sa;
  sa.src[0] = x;   sa.hi[0] = xhi; sa.lo[0] = xlo;
  sa.src[1] = q_w; sa.hi[1] = qwh; sa.lo[1] = qwl;
  sa.src[2] = k_w; sa.hi[2] = kwh; sa.lo[2] = kwl;
  sa.src[3] = v_w; sa.hi[3] = vwh; sa.lo[3] = vwl;
  sa.src[4] = o_w; sa.hi[4] = owh; sa.lo[4] = owl;
  split_k<<<4608, 256, 0, stream>>>(sa);

  GArgs a1;
  a1.Ah = xhi; a1.Al = xlo;
  a1.Wh0 = qwh; a1.Wl0 = qwl; a1.Wh1 = kwh; a1.Wl1 = kwl; a1.Wh2 = vwh; a1.Wl2 = vwl;
  a1.g0 = q_g; a1.b0 = q_b; a1.rm0 = q_rm; a1.rv0 = q_rv;
  a1.g1 = k_g; a1.b1 = k_b; a1.rm1 = k_rm; a1.rv1 = k_rv;
  a1.g2 = v_g; a1.b2 = v_b; a1.rm2 = v_rm; a1.rv2 = v_rv;
  a1.bias = nullptr;
  a1.oq = qspk; a1.ok = kbuf; a1.ov = vbuf; a1.oo = nullptr;
  gemm_f16<0><<<1536, 256, SMEM_BYTES, stream>>>(a1);

  attn_g<<<dim3(32, 8, 4), 256, 0, stream>>>(kbuf, vbuf, pG);
  attn_o<<<dim3(32, 8, 4), 256, 0, stream>>>(qspk, pG, ahi, alo);

  GArgs a2;
  a2.Ah = ahi; a2.Al = alo;
  a2.Wh0 = owh; a2.Wl0 = owl; a2.Wh1 = owh; a2.Wl1 = owl; a2.Wh2 = owh; a2.Wl2 = owl;
  a2.g0 = o_g; a2.b0 = o_b; a2.rm0 = o_rm; a2.rv0 = o_rv;
  a2.g1 = o_g; a2.b1 = o_b; a2.rm1 = o_rm; a2.rv1 = o_rv;
  a2.g2 = o_g; a2.b2 = o_b; a2.rm2 = o_rm; a2.rv2 = o_rv;
  a2.bias = o_bias;
  a2.oq = nullptr; a2.ok = nullptr; a2.ov = nullptr; a2.oo = (float*)d_out;
  gemm_f16<1><<<512, 256, SMEM_BYTES, stream>>>(a2);
}

// Round 7
// 297.028 us; speedup vs baseline: 1.0341x; 1.0341x over previous
//
#include <hip/hip_runtime.h>
#include <math.h>
#include <stdint.h>

#define Bb 8
#define Tt 4
#define Ll 512
#define Dd 512
#define Hh 8
#define HDd 64
#define Mm (Bb*Tt*Ll)   // 16384 rows

typedef _Float16 f16;
typedef _Float16 f16x8 __attribute__((ext_vector_type(8)));
typedef _Float16 f16x4 __attribute__((ext_vector_type(4)));
typedef float f32x16 __attribute__((ext_vector_type(16)));

#define LO_SCALE 2048.0f
#define LO_INV   4.8828125e-4f   // 1/2048 exact

__device__ __forceinline__ void gload16(const void* g, void* l) {
  __builtin_amdgcn_global_load_lds(
      (const __attribute__((address_space(1))) unsigned int*)(uintptr_t)g,
      (__attribute__((address_space(3))) unsigned int*)(uintptr_t)l,
      16, 0, 0);
}

// ---------------- split: f32 -> (hi f16, lo f16 scaled by 2048) ----------------
struct SplitArgs {
  const float* src[5];
  f16* hi[5];
  f16* lo[5];
};

__global__ void split_k(SplitArgs s) {
  int i = blockIdx.x * 256 + threadIdx.x;
  int seg, base;
  if (i < 1048576) { seg = 0; base = i; }
  else { int r = i - 1048576; seg = 1 + (r >> 15); base = r & 32767; }
  const float* sp = s.src[seg] + (size_t)base * 8;
  float4 v0 = *(const float4*)sp;
  float4 v1 = *(const float4*)(sp + 4);
  float a[8] = {v0.x, v0.y, v0.z, v0.w, v1.x, v1.y, v1.z, v1.w};
  f16x8 hv, lv;
  #pragma unroll
  for (int e = 0; e < 8; ++e) {
    f16 hh = (f16)a[e];
    hv[e] = hh;
    lv[e] = (f16)((a[e] - (float)hh) * LO_SCALE);
  }
  *(f16x8*)(s.hi[seg] + (size_t)base * 8) = hv;
  *(f16x8*)(s.lo[seg] + (size_t)base * 8) = lv;
}

// ---------------- f16x2 MFMA GEMM, 32x32x16 frags, 2-barrier loop, fused BN+LIF ----------------
// Row mapping: by in [0,128): b = by>>4, lc32 = by&15.
// tile_row r in [0,128): t = r>>5, rl = r&31; global row = (b*4+t)*512 + lc32*32 + rl.
// LDS swizzle (both sides, rule #21): chunk' = chunk ^ ((row>>1)&3) spreads the
// 8 16B-slot positions over any 8 consecutive rows -> ~2-way (free) on ds_read_b128.
struct GArgs {
  const f16 *Ah, *Al;
  const f16 *Wh0, *Wl0, *Wh1, *Wl1, *Wh2, *Wl2;
  const float *g0,*b0,*rm0,*rv0;
  const float *g1,*b1,*rm1,*rv1;
  const float *g2,*b2,*rm2,*rv2;
  const float* bias;   // MODE==1 only
  f16*   oq;   // MODE0 seg0: q spikes (f16 exact {0,1})
  float* ok;   // MODE0 seg1: relu(BN(k)) f32
  f16*   ov;   // MODE0 seg2: ternary v (f16 exact {-1,0,1})
  float* oo;   // MODE1: final spikes f32 (d_out)
};

#define SMEM_BYTES 34048   // max(32768 staging Ah/Al/Bh/Bl [128][32] f16, 64*133*4 TS)

template<int MODE>
__global__ __launch_bounds__(256, 2)
void gemm_f16(GArgs ar) {
  extern __shared__ __align__(16) char smem[];
  f16* Ah_s = (f16*)smem;                  // [128][32] = 8192 B
  f16* Al_s = (f16*)(smem + 8192);
  f16* Bh_s = (f16*)(smem + 16384);
  f16* Bl_s = (f16*)(smem + 24576);
  float (*TS)[133] = (float(*)[133])smem;  // [64 cols][128 rows + pad] (reuses staging)

  const int tid = threadIdx.x;
  const int lane = tid & 63, wid = tid >> 6;

  // XCD-chunked swizzle: grid is 1D; each XCD gets contiguous row-panels.
  const int bid = blockIdx.x;
  int bx, by;
  if (MODE == 0) { const int sw = (bid & 7) * 192 + (bid >> 3); bx = sw % 12; by = sw / 12; }
  else           { const int sw = (bid & 7) * 64  + (bid >> 3); bx = sw & 3;  by = sw >> 2; }

  const int seg = (MODE == 0) ? (bx >> 2) : 0;
  const int lc0 = (MODE == 0) ? ((bx & 3) << 7) : (bx << 7);
  const int b = by >> 4, lc32 = by & 15;

  const f16* Wh = (seg == 0 ? ar.Wh0 : (seg == 1 ? ar.Wh1 : ar.Wh2));
  const f16* Wl = (seg == 0 ? ar.Wl0 : (seg == 1 ? ar.Wl1 : ar.Wl2));
  const float* gp  = (seg == 0 ? ar.g0  : (seg == 1 ? ar.g1  : ar.g2));
  const float* bp  = (seg == 0 ? ar.b0  : (seg == 1 ? ar.b1  : ar.b2));
  const float* rmp = (seg == 0 ? ar.rm0 : (seg == 1 ? ar.rm1 : ar.rm2));
  const float* rvp = (seg == 0 ? ar.rv0 : (seg == 1 ? ar.rv1 : ar.rv2));

  const int sr = lane >> 2, skc = lane & 3;
  const int skcs = skc ^ ((sr >> 1) & 3);       // source-side chunk swizzle (involution, row bits 1-2)
  const int frow = lane & 31, khalf = lane >> 5;
  const int rsw = (frow >> 1) & 3;              // read-side xor term
  const int wmr = wid >> 1, wnc = wid & 1;      // wave 2x2 -> 64x64 per wave

  f32x16 acc_h[2][2], acc_l[2][2];
  #pragma unroll
  for (int i = 0; i < 2; ++i)
    #pragma unroll
    for (int j = 0; j < 2; ++j) {
      acc_h[i][j] = (f32x16)0.0f;
      acc_l[i][j] = (f32x16)0.0f;
    }

  for (int k0 = 0; k0 < Dd; k0 += 32) {
    __syncthreads();   // readers of previous tile done
    #pragma unroll
    for (int i = 0; i < 2; ++i) {
      const int r = i * 64 + wid * 16 + sr;
      const int growA = (((b << 2) + (r >> 5)) << 9) + (lc32 << 5) + (r & 31);
      const size_t goA = (size_t)growA * Dd + k0 + skcs * 8;
      const size_t goB = (size_t)(lc0 + r) * Dd + k0 + skcs * 8;
      const int lb = i * 2048 + wid * 512;
      gload16(ar.Ah + goA, Ah_s + lb);
      gload16(ar.Al + goA, Al_s + lb);
      gload16(Wh + goB, Bh_s + lb);
      gload16(Wl + goB, Bl_s + lb);
    }
    __syncthreads();   // compiler drains vmcnt before barrier

    f16x8 ah[2][2], al[2][2], bh[2][2], bl[2][2];   // [frag][kstep]
    #pragma unroll
    for (int mi = 0; mi < 2; ++mi) {
      const int r = wmr * 64 + mi * 32 + frow;
      #pragma unroll
      for (int ks = 0; ks < 2; ++ks) {
        const int cin = (khalf + 2 * ks) ^ rsw;
        const int ad = r * 32 + cin * 8;
        ah[mi][ks] = *(const f16x8*)&Ah_s[ad];
        al[mi][ks] = *(const f16x8*)&Al_s[ad];
      }
    }
    #pragma unroll
    for (int nj = 0; nj < 2; ++nj) {
      const int r = wnc * 64 + nj * 32 + frow;
      #pragma unroll
      for (int ks = 0; ks < 2; ++ks) {
        const int cin = (khalf + 2 * ks) ^ rsw;
        const int ad = r * 32 + cin * 8;
        bh[nj][ks] = *(const f16x8*)&Bh_s[ad];
        bl[nj][ks] = *(const f16x8*)&Bl_s[ad];
      }
    }
    #pragma unroll
    for (int ks = 0; ks < 2; ++ks)
      #pragma unroll
      for (int mi = 0; mi < 2; ++mi)
        #pragma unroll
        for (int nj = 0; nj < 2; ++nj) {
          acc_h[mi][nj] = __builtin_amdgcn_mfma_f32_32x32x16_f16(ah[mi][ks], bh[nj][ks], acc_h[mi][nj], 0, 0, 0);
          acc_l[mi][nj] = __builtin_amdgcn_mfma_f32_32x32x16_f16(ah[mi][ks], bl[nj][ks], acc_l[mi][nj], 0, 0, 0);
          acc_l[mi][nj] = __builtin_amdgcn_mfma_f32_32x32x16_f16(al[mi][ks], bh[nj][ks], acc_l[mi][nj], 0, 0, 0);
        }
  }

  // per-column BN constants (2 cols per thread: one per nj-frag)
  float scl[2], shc[2];
  #pragma unroll
  for (int nj = 0; nj < 2; ++nj) {
    const int c = lc0 + wnc * 64 + nj * 32 + frow;
    double S = (double)gp[c] / sqrt((double)rvp[c] + 1e-5);
    double Sh = (double)bp[c] - (double)rmp[c] * S;
    if (MODE == 1) Sh += (double)ar.bias[c] * S;
    scl[nj] = (float)S; shc[nj] = (float)Sh;
  }

  if (MODE == 0 && seg != 0) {
    // direct-write path (k: relu f32, v: ternary f16)
    #pragma unroll
    for (int mi = 0; mi < 2; ++mi)
      #pragma unroll
      for (int nj = 0; nj < 2; ++nj)
        #pragma unroll
        for (int r = 0; r < 16; ++r) {
          const int row32 = (r & 3) + 8 * (r >> 2) + 4 * khalf;
          const int tr = wmr * 64 + mi * 32 + row32;
          const int grow = (((b << 2) + (tr >> 5)) << 9) + (lc32 << 5) + (tr & 31);
          const int col = lc0 + wnc * 64 + nj * 32 + frow;
          float val = acc_h[mi][nj][r] + acc_l[mi][nj][r] * LO_INV;
          float y = val * scl[nj] + shc[nj];
          if (seg == 1) ar.ok[(size_t)grow * Dd + col] = fmaxf(y, 0.f);
          else ar.ov[(size_t)grow * Dd + col] =
                   (f16)((y >= 1.f ? 1.f : 0.f) - (-y >= 1.f ? 1.f : 0.f));
        }
    return;
  }

  // fused BN + LIF epilogue, one 64-col half at a time via TS transpose
  __syncthreads();  // all LDS fragment reads done; safe to reuse smem as TS
  #pragma unroll
  for (int half = 0; half < 2; ++half) {
    if (wnc == half) {
      #pragma unroll
      for (int mi = 0; mi < 2; ++mi)
        #pragma unroll
        for (int nj = 0; nj < 2; ++nj)
          #pragma unroll
          for (int q = 0; q < 4; ++q) {
            float4 yv;
            float* yp = &yv.x;
            #pragma unroll
            for (int rr = 0; rr < 4; ++rr) {
              const int r = q * 4 + rr;
              float val = acc_h[mi][nj][r] + acc_l[mi][nj][r] * LO_INV;
              yp[rr] = val * scl[nj] + shc[nj];
            }
            *(float4*)&TS[nj * 32 + frow][wmr * 64 + mi * 32 + 8 * q + 4 * khalf] = yv;
          }
    }
    __syncthreads();
    const int cc4 = (tid & 15) << 2;
    #pragma unroll
    for (int rr = 0; rr < 2; ++rr) {
      const int rl = (tid >> 4) + (rr << 4);
      float mm[4] = {0.f, 0.f, 0.f, 0.f};
      #pragma unroll
      for (int t = 0; t < 4; ++t) {
        const int trow = t * 32 + rl;
        float sp[4];
        #pragma unroll
        for (int c = 0; c < 4; ++c) {
          float y = TS[cc4 + c][trow];
          float rst = (mm[c] >= 1.f) ? 1.f : 0.f;
          mm[c] = 0.5f * mm[c] + y - rst;
          sp[c] = (mm[c] >= 1.f) ? 1.f : 0.f;
        }
        const size_t go = ((size_t)((((b << 2) + t) << 9) + (lc32 << 5) + rl)) * Dd
                          + lc0 + (half << 6) + cc4;
        if (MODE == 0) {
          f16x4 s4;
          s4[0] = (f16)sp[0]; s4[1] = (f16)sp[1]; s4[2] = (f16)sp[2]; s4[3] = (f16)sp[3];
          *(f16x4*)(ar.oq + go) = s4;
        } else {
          *(float4*)(ar.oo + go) = make_float4(sp[0], sp[1], sp[2], sp[3]);
        }
      }
    }
    __syncthreads();
  }
}

// ---------------- attention phase 1: partial G = 0.125 * k^T v (k f32, v f16) ----------------
__global__ __launch_bounds__(256)
void attn_g(const float* __restrict__ ks, const f16* __restrict__ vs,
            float* __restrict__ pG) {
  const int bt = blockIdx.x, h = blockIdx.y, c = blockIdx.z;
  const float* kp = ks + (size_t)bt * Ll * Dd + h * HDd;
  const f16* vp = vs + (size_t)bt * Ll * Dd + h * HDd;

  __shared__ float KS[64][68];
  __shared__ float VS[64][68];
  const int tid = threadIdx.x;
  const int te = tid & 15, td = tid >> 4;

  float gacc[4][4];
  #pragma unroll
  for (int i = 0; i < 4; ++i)
    #pragma unroll
    for (int j = 0; j < 4; ++j) gacc[i][j] = 0.f;

  for (int mt = 0; mt < 2; ++mt) {
    const int m0 = c * 128 + mt * 64;
    #pragma unroll
    for (int it = 0; it < 4; ++it) {
      int fidx = it * 256 + tid;
      int row = fidx >> 4, fq = fidx & 15;
      *(float4*)&KS[row][fq << 2] = *(const float4*)(kp + (size_t)(m0 + row) * Dd + (fq << 2));
    }
    #pragma unroll
    for (int it = 0; it < 2; ++it) {
      int fidx = it * 256 + tid;
      int row = fidx >> 3, c8 = fidx & 7;
      f16x8 hv = *(const f16x8*)(vp + (size_t)(m0 + row) * Dd + (c8 << 3));
      *(float4*)&VS[row][c8 << 3] = make_float4(hv[0], hv[1], hv[2], hv[3]);
      *(float4*)&VS[row][(c8 << 3) + 4] = make_float4(hv[4], hv[5], hv[6], hv[7]);
    }
    __syncthreads();
    #pragma unroll 4
    for (int mm = 0; mm < 64; ++mm) {
      float4 k4 = *(const float4*)&KS[mm][te << 2];
      float4 v4 = *(const float4*)&VS[mm][td << 2];
      const float kk[4] = {k4.x, k4.y, k4.z, k4.w};
      const float vv[4] = {v4.x, v4.y, v4.z, v4.w};
      #pragma unroll
      for (int i = 0; i < 4; ++i)
        #pragma unroll
        for (int j = 0; j < 4; ++j)
          gacc[i][j] = fmaf(kk[i], vv[j], gacc[i][j]);
    }
    __syncthreads();
  }
  float* out = pG + (((size_t)(bt * 8 + h) * 4 + c) << 12);
  #pragma unroll
  for (int i = 0; i < 4; ++i)
    *(float4*)&out[((te << 2) + i) * 64 + (td << 2)] =
        make_float4(gacc[i][0] * 0.125f, gacc[i][1] * 0.125f,
                    gacc[i][2] * 0.125f, gacc[i][3] * 0.125f);
}

// ---------------- attention phase 2: out = q @ G (q f16 spikes), hi/lo f16 output ----------------
__global__ __launch_bounds__(256)
void attn_o(const f16* __restrict__ qs, const float* __restrict__ pG,
            f16* __restrict__ ahi, f16* __restrict__ alo) {
  const int bt = blockIdx.x, h = blockIdx.y, lc = blockIdx.z;
  __shared__ float G[64][68];
  __shared__ float QS[64][68];
  const int tid = threadIdx.x;

  const float* pg = pG + (((size_t)(bt * 8 + h) * 4) << 12);
  #pragma unroll
  for (int rep = 0; rep < 4; ++rep) {
    int t4 = rep * 256 + tid;
    int e = t4 >> 4, dq = t4 & 15;
    int off = e * 64 + (dq << 2);
    float4 s0 = *(const float4*)(pg + off);
    float4 s1 = *(const float4*)(pg + 4096 + off);
    float4 s2 = *(const float4*)(pg + 8192 + off);
    float4 s3 = *(const float4*)(pg + 12288 + off);
    *(float4*)&G[e][dq << 2] = make_float4(s0.x + s1.x + s2.x + s3.x,
                                           s0.y + s1.y + s2.y + s3.y,
                                           s0.z + s1.z + s2.z + s3.z,
                                           s0.w + s1.w + s2.w + s3.w);
  }
  __syncthreads();

  const f16* qp = qs + (size_t)bt * Ll * Dd + h * HDd;
  const int lr = tid >> 2, dg = tid & 3;

  for (int l0 = 0; l0 < 128; l0 += 64) {
    #pragma unroll
    for (int it = 0; it < 2; ++it) {
      int fidx = it * 256 + tid;
      int row = fidx >> 3, c8 = fidx & 7;
      f16x8 hv = *(const f16x8*)(qp + (size_t)(lc * 128 + l0 + row) * Dd + (c8 << 3));
      *(float4*)&QS[row][c8 << 3] = make_float4(hv[0], hv[1], hv[2], hv[3]);
      *(float4*)&QS[row][(c8 << 3) + 4] = make_float4(hv[4], hv[5], hv[6], hv[7]);
    }
    __syncthreads();
    float oacc[16];
    #pragma unroll
    for (int j = 0; j < 16; ++j) oacc[j] = 0.f;
    for (int ee = 0; ee < 64; ++ee) {
      float qv = QS[lr][ee];
      #pragma unroll
      for (int jq = 0; jq < 4; ++jq) {
        float4 g4 = *(const float4*)&G[ee][(dg << 4) + (jq << 2)];
        oacc[jq * 4 + 0] = fmaf(qv, g4.x, oacc[jq * 4 + 0]);
        oacc[jq * 4 + 1] = fmaf(qv, g4.y, oacc[jq * 4 + 1]);
        oacc[jq * 4 + 2] = fmaf(qv, g4.z, oacc[jq * 4 + 2]);
        oacc[jq * 4 + 3] = fmaf(qv, g4.w, oacc[jq * 4 + 3]);
      }
    }
    f16x8 h0, l0v, h1, l1v;
    #pragma unroll
    for (int t = 0; t < 8; ++t) {
      float v = oacc[t];
      f16 hh = (f16)v;
      h0[t] = hh; l0v[t] = (f16)((v - (float)hh) * LO_SCALE);
      float v2 = oacc[8 + t];
      f16 hh2 = (f16)v2;
      h1[t] = hh2; l1v[t] = (f16)((v2 - (float)hh2) * LO_SCALE);
    }
    size_t ob = ((size_t)bt * Ll + lc * 128 + l0 + lr) * Dd + h * HDd + (dg << 4);
    *(f16x8*)(ahi + ob) = h0;
    *(f16x8*)(ahi + ob + 8) = h1;
    *(f16x8*)(alo + ob) = l0v;
    *(f16x8*)(alo + ob + 8) = l1v;
    __syncthreads();
  }
}

// ---------------- launch ----------------
extern "C" void kernel_launch(void* const* d_in, const int* in_sizes, int n_in,
                              void* d_out, int out_size, void* d_ws, size_t ws_size,
                              hipStream_t stream) {
  const float* x    = (const float*)d_in[0];
  const float* q_w  = (const float*)d_in[1];
  const float* q_g  = (const float*)d_in[2];
  const float* q_b  = (const float*)d_in[3];
  const float* q_rm = (const float*)d_in[4];
  const float* q_rv = (const float*)d_in[5];
  const float* k_w  = (const float*)d_in[6];
  const float* k_g  = (const float*)d_in[7];
  const float* k_b  = (const float*)d_in[8];
  const float* k_rm = (const float*)d_in[9];
  const float* k_rv = (const float*)d_in[10];
  const float* v_w  = (const float*)d_in[11];
  const float* v_g  = (const float*)d_in[12];
  const float* v_b  = (const float*)d_in[13];
  const float* v_rm = (const float*)d_in[14];
  const float* v_rv = (const float*)d_in[15];
  const float* o_w  = (const float*)d_in[16];
  const float* o_bias = (const float*)d_in[17];
  const float* o_g  = (const float*)d_in[18];
  const float* o_b  = (const float*)d_in[19];
  const float* o_rm = (const float*)d_in[20];
  const float* o_rv = (const float*)d_in[21];

  char* wsb = (char*)d_ws;
  const size_t R16 = 16777216;            // 16 MB = one NBUF of f16
  f16*   xhi  = (f16*)wsb;                // dead after QKV -> reused as ahi
  f16*   xlo  = (f16*)(wsb + R16);        // dead after QKV -> reused as alo
  f16*   qspk = (f16*)(wsb + 2 * R16);    // q spikes f16
  float* kbuf = (float*)(wsb + 3 * R16);  // relu(BN(k)) f32 (2 regions)
  f16*   vbuf = (f16*)(wsb + 5 * R16);    // ternary v f16
  float* pG   = (float*)(wsb + 6 * R16);  // partial G f32
  f16*   wsp  = (f16*)(wsb + 7 * R16);    // 8 x 262144 f16 = 4 MB weight splits
  f16* qwh = wsp;            f16* qwl = wsp + 262144;
  f16* kwh = wsp + 2*262144; f16* kwl = wsp + 3*262144;
  f16* vwh = wsp + 4*262144; f16* vwl = wsp + 5*262144;
  f16* owh = wsp + 6*262144; f16* owl = wsp + 7*262144;
  f16* ahi = xhi;
  f16* alo = xlo;

  SplitArgs sa;
  sa.src[0] = x;   sa.hi[0] = xhi; sa.lo[0] = xlo;
  sa.src[1] = q_w; sa.hi[1] = qwh; sa.lo[1] = qwl;
  sa.src[2] = k_w; sa.hi[2] = kwh; sa.lo[2] = kwl;
  sa.src[3] = v_w; sa.hi[3] = vwh; sa.lo[3] = vwl;
  sa.src[4] = o_w; sa.hi[4] = owh; sa.lo[4] = owl;
  split_k<<<4608, 256, 0, stream>>>(sa);

  GArgs a1;
  a1.Ah = xhi; a1.Al = xlo;
  a1.Wh0 = qwh; a1.Wl0 = qwl; a1.Wh1 = kwh; a1.Wl1 = kwl; a1.Wh2 = vwh; a1.Wl2 = vwl;
  a1.g0 = q_g; a1.b0 = q_b; a1.rm0 = q_rm; a1.rv0 = q_rv;
  a1.g1 = k_g; a1.b1 = k_b; a1.rm1 = k_rm; a1.rv1 = k_rv;
  a1.g2 = v_g; a1.b2 = v_b; a1.rm2 = v_rm; a1.rv2 = v_rv;
  a1.bias = nullptr;
  a1.oq = qspk; a1.ok = kbuf; a1.ov = vbuf; a1.oo = nullptr;
  gemm_f16<0><<<1536, 256, SMEM_BYTES, stream>>>(a1);

  attn_g<<<dim3(32, 8, 4), 256, 0, stream>>>(kbuf, vbuf, pG);
  attn_o<<<dim3(32, 8, 4), 256, 0, stream>>>(qspk, pG, ahi, alo);

  GArgs a2;
  a2.Ah = ahi; a2.Al = alo;
  a2.Wh0 = owh; a2.Wl0 = owl; a2.Wh1 = owh; a2.Wl1 = owl; a2.Wh2 = owh; a2.Wl2 = owl;
  a2.g0 = o_g; a2.b0 = o_b; a2.rm0 = o_rm; a2.rv0 = o_rv;
  a2.g1 = o_g; a2.b1 = o_b; a2.rm1 = o_rm; a2.rv1 = o_rv;
  a2.g2 = o_g; a2.b2 = o_b; a2.rm2 = o_rm; a2.rv2 = o_rv;
  a2.bias = o_bias;
  a2.oq = nullptr; a2.ok = nullptr; a2.ov = nullptr; a2.oo = (float*)d_out;
  gemm_f16<1><<<512, 256, SMEM_BYTES, stream>>>(a2);
}